// Round 1
// baseline (849.178 us; speedup 1.0000x reference)
//
#include <hip/hip_runtime.h>

#define B_ 4
#define H_ 16
#define D_ 64
#define E_ 1024
#define SQ_ 2048
#define SKV_ 2049
#define SKVP_ 2080

typedef __attribute__((ext_vector_type(8))) short short8;
typedef __attribute__((ext_vector_type(4))) float f32x4;

static __device__ __forceinline__ unsigned short f2bf(float f) {
    unsigned int u = __float_as_uint(f);
    u += 0x7FFFu + ((u >> 16) & 1u);
    return (unsigned short)(u >> 16);
}

static __device__ __forceinline__ f32x4 mfma16(short8 a, short8 b, f32x4 c) {
    return __builtin_amdgcn_mfma_f32_16x16x32_bf16(a, b, c, 0, 0, 0);
}

// ---------------------------------------------------------------------------
// Mask decode: sniff dtype (uint8 bool vs int32/f32 0/1 words), write uint8.
// ---------------------------------------------------------------------------
__global__ void decode_mask_kernel(const void* __restrict__ mraw,
                                   unsigned char* __restrict__ condm) {
    __shared__ int flags[2];  // [0] all-words-in-{0,1}, [1] all-words-in-{0,1.0f}
    const int t = threadIdx.x;
    if (t < 2) flags[t] = 1;
    __syncthreads();
    const unsigned int* wp = (const unsigned int*)mraw;
    int okI = 1, okF = 1;
    for (int i = t; i < 2048; i += 256) {   // first 8KB: safe for all dtypes
        unsigned int w = wp[i];
        if (w > 1u) okI = 0;
        if (w != 0u && w != 0x3F800000u) okF = 0;
    }
    if (!okI) atomicAnd(&flags[0], 0);
    if (!okF) atomicAnd(&flags[1], 0);
    __syncthreads();
    const int isWord = flags[0] | flags[1];  // 4-byte elements (int32 or f32)
    for (int i = t; i < B_ * SQ_; i += 256) {
        unsigned char v;
        if (isWord) v = (unsigned char)(wp[i] != 0u);
        else        v = (unsigned char)(((const unsigned char*)mraw)[i] != 0);
        condm[i] = v;
    }
}

// ---------------------------------------------------------------------------
// GEMM: C = A @ W^T + bias.  A rows in (seq,b) order, E=1024 cols, K=1024.
// MODE 0: A=f32 q,  out bf16 Q   (b,h,sq,64)
// MODE 1: A=f32 kv, out bf16 K   (b,h,kvp,64)
// MODE 2: A=f32 kv, out bf16 V^T (b,h,64,kvp)
// MODE 3: A=bf16 out_pre (rows (sq,b)), out f32 d_out rows (sq,b)
// ---------------------------------------------------------------------------
template <int MODE>
__global__ __launch_bounds__(256, 2)
void gemm_kernel(const void* __restrict__ Ain, const float* __restrict__ W,
                 const float* __restrict__ bias, void* __restrict__ Outp, int nrows) {
    __shared__ unsigned short As[64][40];
    __shared__ unsigned short Ws[64][40];
    const int t = threadIdx.x;
    const int row0 = blockIdx.x * 64;
    const int col0 = blockIdx.y * 64;
    const int w = t >> 6, lane = t & 63;
    const int wm = w >> 1, wn = w & 1;
    const int lr = lane & 15, lg = lane >> 4, lk = lg * 8;
    const int srow = t >> 2, sk = (t & 3) * 8;
    int arow = row0 + srow;
    if (arow >= nrows) arow = nrows - 1;
    const int wrow = col0 + srow;

    f32x4 acc[2][2] = {};

#pragma unroll 1
    for (int k0 = 0; k0 < E_; k0 += 32) {
        if constexpr (MODE == 3) {
            const unsigned short* A = (const unsigned short*)Ain;
            *(short8*)&As[srow][sk] = *(const short8*)&A[(size_t)arow * E_ + k0 + sk];
        } else {
            const float* A = (const float*)Ain;
            const float* ap = &A[(size_t)arow * E_ + k0 + sk];
            short8 v;
#pragma unroll
            for (int i = 0; i < 8; ++i) v[i] = (short)f2bf(ap[i]);
            *(short8*)&As[srow][sk] = v;
        }
        {
            const float* wpr = &W[(size_t)wrow * E_ + k0 + sk];
            short8 v;
#pragma unroll
            for (int i = 0; i < 8; ++i) v[i] = (short)f2bf(wpr[i]);
            *(short8*)&Ws[srow][sk] = v;
        }
        __syncthreads();
        short8 a0 = *(const short8*)&As[wm * 32 + lr][lk];
        short8 a1 = *(const short8*)&As[wm * 32 + 16 + lr][lk];
        short8 b0 = *(const short8*)&Ws[wn * 32 + lr][lk];
        short8 b1 = *(const short8*)&Ws[wn * 32 + 16 + lr][lk];
        acc[0][0] = mfma16(a0, b0, acc[0][0]);
        acc[0][1] = mfma16(a0, b1, acc[0][1]);
        acc[1][0] = mfma16(a1, b0, acc[1][0]);
        acc[1][1] = mfma16(a1, b1, acc[1][1]);
        __syncthreads();
    }

#pragma unroll
    for (int ni = 0; ni < 2; ++ni) {
        const int c = col0 + wn * 32 + ni * 16 + lr;
        const float bv = bias[c];
#pragma unroll
        for (int mi = 0; mi < 2; ++mi) {
#pragma unroll
            for (int r4 = 0; r4 < 4; ++r4) {
                const int r = row0 + wm * 32 + mi * 16 + lg * 4 + r4;
                if (r >= nrows) continue;
                const float v = acc[mi][ni][r4] + bv;
                if constexpr (MODE == 0) {
                    const int sq = r >> 2, b = r & 3;
                    const int h = c >> 6, d = c & 63;
                    ((unsigned short*)Outp)[(((size_t)(b * H_ + h) * SQ_) + sq) * D_ + d] = f2bf(v);
                } else if constexpr (MODE == 1) {
                    const int kvi = r >> 2, b = r & 3;
                    const int h = c >> 6, d = c & 63;
                    ((unsigned short*)Outp)[(((size_t)(b * H_ + h) * SKVP_) + kvi) * D_ + d] = f2bf(v);
                } else if constexpr (MODE == 2) {
                    const int kvi = r >> 2, b = r & 3;
                    const int h = c >> 6, d = c & 63;
                    ((unsigned short*)Outp)[(((size_t)(b * H_ + h) * D_) + d) * SKVP_ + kvi] = f2bf(v);
                } else {
                    ((float*)Outp)[(size_t)r * E_ + c] = v;
                }
            }
        }
    }
}

// ---------------------------------------------------------------------------
// Zero the kv padding rows/cols (2049..2079) of K and V^T.
// ---------------------------------------------------------------------------
__global__ void zero_pad_kernel(unsigned short* __restrict__ Kb,
                                unsigned short* __restrict__ Vt) {
    const int idx = blockIdx.x * blockDim.x + threadIdx.x;
    const int NK = 64 * 31 * 64;
    if (idx < NK) {
        const int bh = idx / (31 * 64);
        const int rem = idx - bh * 31 * 64;
        const int kvi = SKV_ + rem / 64;
        const int d = rem & 63;
        Kb[((size_t)bh * SKVP_ + kvi) * D_ + d] = 0;
    } else {
        const int j = idx - NK;
        if (j < 4096 * 31) {
            const int row = j / 31;  // bh*64 + d
            const int kvi = SKV_ + (j - row * 31);
            Vt[(size_t)row * SKVP_ + kvi] = 0;
        }
    }
}

// ---------------------------------------------------------------------------
// Flash attention forward: per (b,h,64 q rows). Writes out_pre + (m,l) stats.
// ---------------------------------------------------------------------------
__global__ __launch_bounds__(256, 2)
void attn_fwd_kernel(const unsigned short* __restrict__ Qb, const unsigned short* __restrict__ Kb,
                     const unsigned short* __restrict__ Vt, const unsigned char* __restrict__ condm,
                     unsigned short* __restrict__ OP, float* __restrict__ Mst,
                     float* __restrict__ Lst) {
    const int h = blockIdx.y, b = blockIdx.z;
    const int bh = b * H_ + h;
    const int t = threadIdx.x, w = t >> 6, lane = t & 63;
    const int lr = lane & 15, lg = lane >> 4, lk = lg * 8;
    const int qbase = blockIdx.x * 64 + w * 16;

    __shared__ unsigned short Ks[32][72];
    __shared__ unsigned short Vs[64][40];
    __shared__ unsigned short Ps[4][16][40];

    const size_t qoff = ((size_t)bh * SQ_ + qbase + lr) * D_;
    const short8 qf0 = *(const short8*)&Qb[qoff + lk];
    const short8 qf1 = *(const short8*)&Qb[qoff + 32 + lk];

    int qrow[4], ci[4];
    float m[4], l[4];
    f32x4 Of[4] = {};
#pragma unroll
    for (int r = 0; r < 4; ++r) {
        qrow[r] = qbase + lg * 4 + r;
        ci[r] = condm[b * SQ_ + qrow[r]];
        m[r] = -__builtin_inff();
        l[r] = 0.f;
    }

    const int skey = t >> 3, sdc = (t & 7) * 8;
    const int svd = t >> 2, svk = (t & 3) * 8;
    const f32x4 zz = {0.f, 0.f, 0.f, 0.f};

#pragma unroll 1
    for (int kv0 = 0; kv0 < SKVP_; kv0 += 32) {
        __syncthreads();
        *(short8*)&Ks[skey][sdc] = *(const short8*)&Kb[((size_t)bh * SKVP_ + kv0 + skey) * D_ + sdc];
        *(short8*)&Vs[svd][svk] = *(const short8*)&Vt[((size_t)bh * D_ + svd) * SKVP_ + kv0 + svk];
        __syncthreads();

        f32x4 S[2];
#pragma unroll
        for (int ni = 0; ni < 2; ++ni) {
            short8 kb0 = *(const short8*)&Ks[ni * 16 + lr][lk];
            short8 kb1 = *(const short8*)&Ks[ni * 16 + lr][32 + lk];
            S[ni] = mfma16(qf0, kb0, zz);
            S[ni] = mfma16(qf1, kb1, S[ni]);
        }

        float sc[2][4];
#pragma unroll
        for (int ni = 0; ni < 2; ++ni) {
            const int k = kv0 + ni * 16 + lr;
            int cj = 0, jvalid = 0;
            if (k >= 1 && k < SKV_) { cj = condm[b * SQ_ + (k - 1)]; jvalid = 1; }
#pragma unroll
            for (int r = 0; r < 4; ++r) {
                const float s = S[ni][r] * 0.125f;
                bool masked;
                if (k == 0) masked = false;
                else if (!jvalid) masked = true;
                else masked = ci[r] ? (cj == 0) : (qrow[r] < (k - 1));
                sc[ni][r] = masked ? -__builtin_inff() : s;
            }
        }

        float p[2][4];
#pragma unroll
        for (int r = 0; r < 4; ++r) {
            float v = fmaxf(sc[0][r], sc[1][r]);
#pragma unroll
            for (int off = 1; off < 16; off <<= 1) v = fmaxf(v, __shfl_xor(v, off));
            const float mn = fmaxf(m[r], v);
            const float p0 = (sc[0][r] == -__builtin_inff()) ? 0.f : __expf(sc[0][r] - mn);
            const float p1 = (sc[1][r] == -__builtin_inff()) ? 0.f : __expf(sc[1][r] - mn);
            p[0][r] = p0;
            p[1][r] = p1;
            float s2 = p0 + p1;
#pragma unroll
            for (int off = 1; off < 16; off <<= 1) s2 += __shfl_xor(s2, off);
            const float alpha = (m[r] == -__builtin_inff()) ? 0.f : __expf(m[r] - mn);
            l[r] = l[r] * alpha + s2;
            m[r] = mn;
#pragma unroll
            for (int nt = 0; nt < 4; ++nt) Of[nt][r] *= alpha;
        }

#pragma unroll
        for (int ni = 0; ni < 2; ++ni)
#pragma unroll
            for (int r = 0; r < 4; ++r)
                Ps[w][lg * 4 + r][ni * 16 + lr] = f2bf(p[ni][r]);

        const short8 pa = *(const short8*)&Ps[w][lr][lk];
#pragma unroll
        for (int nt = 0; nt < 4; ++nt) {
            short8 vb = *(const short8*)&Vs[nt * 16 + lr][lk];
            Of[nt] = mfma16(pa, vb, Of[nt]);
        }
    }

    float inv[4];
#pragma unroll
    for (int r = 0; r < 4; ++r) inv[r] = 1.0f / l[r];
#pragma unroll
    for (int nt = 0; nt < 4; ++nt)
#pragma unroll
        for (int r = 0; r < 4; ++r)
            OP[((size_t)qrow[r] * B_ + b) * E_ + h * D_ + nt * 16 + lr] = f2bf(Of[nt][r] * inv[r]);
    if (lr == 0)
#pragma unroll
        for (int r = 0; r < 4; ++r) {
            Mst[(size_t)bh * SQ_ + qrow[r]] = m[r];
            Lst[(size_t)bh * SQ_ + qrow[r]] = l[r];
        }
}

// ---------------------------------------------------------------------------
// attn-mean pass: recompute scores per (b, q-tile, k-tile), sum over heads.
// ---------------------------------------------------------------------------
__global__ __launch_bounds__(256, 2)
void attn_probs_kernel(const unsigned short* __restrict__ Qb, const unsigned short* __restrict__ Kb,
                       const float* __restrict__ Mst, const float* __restrict__ Lst,
                       const unsigned char* __restrict__ condm, float* __restrict__ out1) {
    const int kv0 = blockIdx.x * 32;
    const int b = blockIdx.z;
    const int t = threadIdx.x, w = t >> 6, lane = t & 63;
    const int lr = lane & 15, lg = lane >> 4, lk = lg * 8;
    const int qbase = blockIdx.y * 64 + w * 16;

    __shared__ unsigned short Ks[32][72];

    int qrow[4], ci[4];
#pragma unroll
    for (int r = 0; r < 4; ++r) {
        qrow[r] = qbase + lg * 4 + r;
        ci[r] = condm[b * SQ_ + qrow[r]];
    }

    bool msk[2][4];
#pragma unroll
    for (int ni = 0; ni < 2; ++ni) {
        const int k = kv0 + ni * 16 + lr;
        int cj = 0, jvalid = 0;
        if (k >= 1 && k < SKV_) { cj = condm[b * SQ_ + k - 1]; jvalid = 1; }
#pragma unroll
        for (int r = 0; r < 4; ++r) {
            if (k == 0) msk[ni][r] = false;
            else if (!jvalid) msk[ni][r] = true;
            else msk[ni][r] = ci[r] ? (cj == 0) : (qrow[r] < (k - 1));
        }
    }

    float acc[2][4] = {};
    const int skey = t >> 3, sdc = (t & 7) * 8;
    const f32x4 zz = {0.f, 0.f, 0.f, 0.f};

#pragma unroll 1
    for (int h = 0; h < H_; ++h) {
        const int bh = b * H_ + h;
        __syncthreads();
        *(short8*)&Ks[skey][sdc] = *(const short8*)&Kb[((size_t)bh * SKVP_ + kv0 + skey) * D_ + sdc];
        __syncthreads();
        const size_t qoff = ((size_t)bh * SQ_ + qbase + lr) * D_;
        const short8 qf0 = *(const short8*)&Qb[qoff + lk];
        const short8 qf1 = *(const short8*)&Qb[qoff + 32 + lk];
        f32x4 S[2];
#pragma unroll
        for (int ni = 0; ni < 2; ++ni) {
            short8 kb0 = *(const short8*)&Ks[ni * 16 + lr][lk];
            short8 kb1 = *(const short8*)&Ks[ni * 16 + lr][32 + lk];
            S[ni] = mfma16(qf0, kb0, zz);
            S[ni] = mfma16(qf1, kb1, S[ni]);
        }
        float mr[4], li[4];
#pragma unroll
        for (int r = 0; r < 4; ++r) {
            mr[r] = Mst[(size_t)bh * SQ_ + qrow[r]];
            li[r] = 1.0f / Lst[(size_t)bh * SQ_ + qrow[r]];
        }
#pragma unroll
        for (int ni = 0; ni < 2; ++ni)
#pragma unroll
            for (int r = 0; r < 4; ++r)
                if (!msk[ni][r]) acc[ni][r] += __expf(S[ni][r] * 0.125f - mr[r]) * li[r];
    }

#pragma unroll
    for (int ni = 0; ni < 2; ++ni) {
        const int k = kv0 + ni * 16 + lr;
        if (k < SKV_) {
#pragma unroll
            for (int r = 0; r < 4; ++r)
                out1[((size_t)b * SQ_ + qrow[r]) * SKV_ + k] = acc[ni][r] * (1.0f / 16.0f);
        }
    }
}

// ---------------------------------------------------------------------------
extern "C" void kernel_launch(void* const* d_in, const int* in_sizes, int n_in,
                              void* d_out, int out_size, void* d_ws, size_t ws_size,
                              hipStream_t stream) {
    const float* q   = (const float*)d_in[0];
    const float* kv  = (const float*)d_in[1];
    const void*  msk = d_in[2];
    const float* Wq  = (const float*)d_in[3];
    const float* bq  = (const float*)d_in[4];
    const float* Wk  = (const float*)d_in[5];
    const float* bk  = (const float*)d_in[6];
    const float* Wv  = (const float*)d_in[7];
    const float* bv  = (const float*)d_in[8];
    const float* Wo  = (const float*)d_in[9];
    const float* bo  = (const float*)d_in[10];

    char* ws = (char*)d_ws;
    unsigned short* Qb  = (unsigned short*)(ws);              // 16,777,216 B
    unsigned short* Kb  = (unsigned short*)(ws + 16777216);   // 17,039,360 B
    unsigned short* Vt  = (unsigned short*)(ws + 33816576);   // 17,039,360 B
    unsigned short* OP  = (unsigned short*)(ws + 50855936);   // 16,777,216 B
    float*          Mst = (float*)(ws + 67633152);            //    524,288 B
    float*          Lst = (float*)(ws + 68157440);            //    524,288 B
    unsigned char* condm = (unsigned char*)(ws + 68681728);   //      8,192 B

    float* out0 = (float*)d_out;
    float* out1 = out0 + (size_t)SQ_ * B_ * E_;

    decode_mask_kernel<<<1, 256, 0, stream>>>(msk, condm);
    gemm_kernel<0><<<dim3(128, 16), 256, 0, stream>>>((const void*)q, Wq, bq, (void*)Qb, SQ_ * B_);
    gemm_kernel<1><<<dim3(129, 16), 256, 0, stream>>>((const void*)kv, Wk, bk, (void*)Kb, SKV_ * B_);
    gemm_kernel<2><<<dim3(129, 16), 256, 0, stream>>>((const void*)kv, Wv, bv, (void*)Vt, SKV_ * B_);
    zero_pad_kernel<<<992, 256, 0, stream>>>(Kb, Vt);
    attn_fwd_kernel<<<dim3(32, 16, 4), 256, 0, stream>>>(Qb, Kb, Vt, condm, OP, Mst, Lst);
    attn_probs_kernel<<<dim3(65, 32, 4), 256, 0, stream>>>(Qb, Kb, Mst, Lst, condm, out1);
    gemm_kernel<3><<<dim3(128, 16), 256, 0, stream>>>((const void*)OP, Wo, bo, (void*)out0, SQ_ * B_);
}

// Round 4
// 629.628 us; speedup vs baseline: 1.3487x; 1.3487x over previous
//
#include <hip/hip_runtime.h>

#define B_ 4
#define H_ 16
#define D_ 64
#define E_ 1024
#define SQ_ 2048
#define SKV_ 2049
#define SKVP_ 2080

typedef __attribute__((ext_vector_type(8))) short short8;
typedef __attribute__((ext_vector_type(4))) float f32x4;
typedef __attribute__((ext_vector_type(16))) float f32x16;
typedef __attribute__((ext_vector_type(4))) unsigned int u32x4;

static __device__ __forceinline__ unsigned short f2bf(float f) {
    unsigned int u = __float_as_uint(f);
    u += 0x7FFFu + ((u >> 16) & 1u);
    return (unsigned short)(u >> 16);
}
static __device__ __forceinline__ unsigned int pack2(float a, float b) {
    return (unsigned int)f2bf(a) | ((unsigned int)f2bf(b) << 16);
}

static __device__ __forceinline__ f32x4 mfma16(short8 a, short8 b, f32x4 c) {
    return __builtin_amdgcn_mfma_f32_16x16x32_bf16(a, b, c, 0, 0, 0);
}
static __device__ __forceinline__ f32x16 mfma32(short8 a, short8 b, f32x16 c) {
    return __builtin_amdgcn_mfma_f32_32x32x16_bf16(a, b, c, 0, 0, 0);
}

// ---------------------------------------------------------------------------
// Mask decode: sniff dtype (uint8 bool vs int32/f32 0/1 words), write uint8.
// ---------------------------------------------------------------------------
__global__ void decode_mask_kernel(const void* __restrict__ mraw,
                                   unsigned char* __restrict__ condm) {
    __shared__ int flags[2];
    const int t = threadIdx.x;
    if (t < 2) flags[t] = 1;
    __syncthreads();
    const unsigned int* wp = (const unsigned int*)mraw;
    int okI = 1, okF = 1;
    for (int i = t; i < 2048; i += 256) {
        unsigned int w = wp[i];
        if (w > 1u) okI = 0;
        if (w != 0u && w != 0x3F800000u) okF = 0;
    }
    if (!okI) atomicAnd(&flags[0], 0);
    if (!okF) atomicAnd(&flags[1], 0);
    __syncthreads();
    const int isWord = flags[0] | flags[1];
    for (int i = t; i < B_ * SQ_; i += 256) {
        unsigned char v;
        if (isWord) v = (unsigned char)(wp[i] != 0u);
        else        v = (unsigned char)(((const unsigned char*)mraw)[i] != 0);
        condm[i] = v;
    }
}

// ---------------------------------------------------------------------------
// GEMM: C = A @ W^T + bias.  (MODE 0 additionally scales by 1/8 = 1/sqrt(64))
// ---------------------------------------------------------------------------
template <int MODE>
__global__ __launch_bounds__(256, 2)
void gemm_kernel(const void* __restrict__ Ain, const float* __restrict__ W,
                 const float* __restrict__ bias, void* __restrict__ Outp, int nrows) {
    __shared__ unsigned short As[64][40];
    __shared__ unsigned short Ws[64][40];
    const int t = threadIdx.x;
    const int row0 = blockIdx.x * 64;
    const int col0 = blockIdx.y * 64;
    const int w = t >> 6, lane = t & 63;
    const int wm = w >> 1, wn = w & 1;
    const int lr = lane & 15, lg = lane >> 4, lk = lg * 8;
    const int srow = t >> 2, sk = (t & 3) * 8;
    int arow = row0 + srow;
    if (arow >= nrows) arow = nrows - 1;
    const int wrow = col0 + srow;

    f32x4 acc[2][2] = {};

#pragma unroll 1
    for (int k0 = 0; k0 < E_; k0 += 32) {
        if constexpr (MODE == 3) {
            const unsigned short* A = (const unsigned short*)Ain;
            *(short8*)&As[srow][sk] = *(const short8*)&A[(size_t)arow * E_ + k0 + sk];
        } else {
            const float* A = (const float*)Ain;
            const float* ap = &A[(size_t)arow * E_ + k0 + sk];
            short8 v;
#pragma unroll
            for (int i = 0; i < 8; ++i) v[i] = (short)f2bf(ap[i]);
            *(short8*)&As[srow][sk] = v;
        }
        {
            const float* wpr = &W[(size_t)wrow * E_ + k0 + sk];
            short8 v;
#pragma unroll
            for (int i = 0; i < 8; ++i) v[i] = (short)f2bf(wpr[i]);
            *(short8*)&Ws[srow][sk] = v;
        }
        __syncthreads();
        short8 a0 = *(const short8*)&As[wm * 32 + lr][lk];
        short8 a1 = *(const short8*)&As[wm * 32 + 16 + lr][lk];
        short8 b0 = *(const short8*)&Ws[wn * 32 + lr][lk];
        short8 b1 = *(const short8*)&Ws[wn * 32 + 16 + lr][lk];
        acc[0][0] = mfma16(a0, b0, acc[0][0]);
        acc[0][1] = mfma16(a0, b1, acc[0][1]);
        acc[1][0] = mfma16(a1, b0, acc[1][0]);
        acc[1][1] = mfma16(a1, b1, acc[1][1]);
        __syncthreads();
    }

#pragma unroll
    for (int ni = 0; ni < 2; ++ni) {
        const int c = col0 + wn * 32 + ni * 16 + lr;
        const float bv = bias[c];
#pragma unroll
        for (int mi = 0; mi < 2; ++mi) {
#pragma unroll
            for (int r4 = 0; r4 < 4; ++r4) {
                const int r = row0 + wm * 32 + mi * 16 + lg * 4 + r4;
                if (r >= nrows) continue;
                float v = acc[mi][ni][r4] + bv;
                if constexpr (MODE == 0) {
                    v *= 0.125f;  // fold 1/sqrt(head_dim) into Q
                    const int sq = r >> 2, b = r & 3;
                    const int h = c >> 6, d = c & 63;
                    ((unsigned short*)Outp)[(((size_t)(b * H_ + h) * SQ_) + sq) * D_ + d] = f2bf(v);
                } else if constexpr (MODE == 1) {
                    const int kvi = r >> 2, b = r & 3;
                    const int h = c >> 6, d = c & 63;
                    ((unsigned short*)Outp)[(((size_t)(b * H_ + h) * SKVP_) + kvi) * D_ + d] = f2bf(v);
                } else if constexpr (MODE == 2) {
                    const int kvi = r >> 2, b = r & 3;
                    const int h = c >> 6, d = c & 63;
                    ((unsigned short*)Outp)[(((size_t)(b * H_ + h) * D_) + d) * SKVP_ + kvi] = f2bf(v);
                } else {
                    ((float*)Outp)[(size_t)r * E_ + c] = v;
                }
            }
        }
    }
}

// ---------------------------------------------------------------------------
// Zero the kv padding rows/cols (2049..2079) of K and V^T.
// ---------------------------------------------------------------------------
__global__ void zero_pad_kernel(unsigned short* __restrict__ Kb,
                                unsigned short* __restrict__ Vt) {
    const int idx = blockIdx.x * blockDim.x + threadIdx.x;
    const int NK = 64 * 31 * 64;
    if (idx < NK) {
        const int bh = idx / (31 * 64);
        const int rem = idx - bh * 31 * 64;
        const int kvi = SKV_ + rem / 64;
        const int d = rem & 63;
        Kb[((size_t)bh * SKVP_ + kvi) * D_ + d] = 0;
    } else {
        const int j = idx - NK;
        if (j < 4096 * 31) {
            const int row = j / 31;
            const int kvi = SKV_ + (j - row * 31);
            Vt[(size_t)row * SKVP_ + kvi] = 0;
        }
    }
}

// ---------------------------------------------------------------------------
// Flash attention fwd, swapped-operand 32x32 structure.
// Cross-lane ops via __shfl_xor(.,32) only (known-good primitives).
// ---------------------------------------------------------------------------
__global__ __launch_bounds__(256, 4)
void attn_fwd_kernel(const unsigned short* __restrict__ Qb, const unsigned short* __restrict__ Kb,
                     const unsigned short* __restrict__ Vt, const unsigned char* __restrict__ condm,
                     unsigned short* __restrict__ OP, float* __restrict__ Mst,
                     float* __restrict__ Lst) {
    const int h = blockIdx.y, b = blockIdx.z;
    const int bh = b * H_ + h;
    const int t = threadIdx.x, w = t >> 6, lane = t & 63;
    const int ql = lane & 31;
    const int hi = lane >> 5;
    const int qg = blockIdx.x * 128 + w * 32 + ql;

    __shared__ unsigned short Ks[32 * 64];   // XOR-swizzled, 16B granules
    __shared__ unsigned short Vs[64][40];    // padded rows (2-way only)
    __shared__ unsigned int cjb[65];

    for (int g = t; g < 65; g += 256) {
        unsigned int wbits = 0;
        const int base = g * 32;
#pragma unroll 4
        for (int i = 0; i < 32; ++i) {
            const int kv = base + i;
            if (kv >= 1 && kv < SKV_) wbits |= ((unsigned int)condm[b * SQ_ + kv - 1]) << i;
        }
        cjb[g] = wbits;
    }

    const size_t qoff = ((size_t)bh * SQ_ + qg) * D_;
    short8 qf[4];
#pragma unroll
    for (int tt = 0; tt < 4; ++tt) qf[tt] = *(const short8*)&Qb[qoff + tt * 16 + hi * 8];

    const unsigned int ci = condm[b * SQ_ + qg];

    float m = -__builtin_inff(), l = 0.f;
    f32x16 o0 = {}, o1 = {};

    const int krow = t >> 3, kseg = t & 7;
    const int vrow = t >> 2, vpart = t & 3;
    const unsigned short* Kbase = &Kb[(size_t)bh * SKVP_ * D_];
    const unsigned short* Vbase = &Vt[(size_t)bh * D_ * SKVP_];

#pragma unroll 1
    for (int kv0 = 0; kv0 < SKVP_; kv0 += 32) {
        __syncthreads();
        *(short8*)&Ks[krow * 64 + ((kseg ^ (krow & 7)) * 8)] =
            *(const short8*)&Kbase[(size_t)(kv0 + krow) * D_ + kseg * 8];
        *(short8*)&Vs[vrow][vpart * 8] =
            *(const short8*)&Vbase[(size_t)vrow * SKVP_ + kv0 + vpart * 8];
        __syncthreads();

        // S^T = K @ Q^T  (col = q = ql, row = k)
        f32x16 S = {};
#pragma unroll
        for (int tt = 0; tt < 4; ++tt) {
            const short8 kf = *(const short8*)&Ks[ql * 64 + (((2 * tt + hi) ^ (ql & 7)) * 8)];
            S = mfma32(kf, qf[tt], S);
        }

        // mask bits: bit i => kv0+i masked for this q-row
        const unsigned int cjw = cjb[kv0 >> 5];
        const int T = qg + 1 - kv0;
        unsigned int causalw;
        if (T < 0) causalw = ~0u;
        else if (T >= 31) causalw = 0u;
        else causalw = (~0u) << (T + 1);
        unsigned int mb = ci ? ~cjw : causalw;
        if (kv0 == 0) mb &= ~1u;     // text column always visible
        const unsigned int mbs = mb >> (hi * 4);

        float rmax = -__builtin_inff();
#pragma unroll
        for (int r = 0; r < 16; ++r) {
            const int kc = (r & 3) + 8 * (r >> 2);
            const float s = ((mbs >> kc) & 1u) ? -__builtin_inff() : S[r];
            S[r] = s;
            rmax = fmaxf(rmax, s);
        }
        rmax = fmaxf(rmax, __shfl_xor(rmax, 32));
        const float mn = fmaxf(m, rmax);
        float psum = 0.f;
#pragma unroll
        for (int r = 0; r < 16; ++r) {
            const float p = __expf(S[r] - mn);   // exp(-inf)=0 for masked
            S[r] = p;
            psum += p;
        }
        psum += __shfl_xor(psum, 32);
        const float alpha = __expf(m - mn);
        l = l * alpha + psum;
        m = mn;
        o0 *= alpha;
        o1 *= alpha;

        // pack P pairs to bf16 words (k = crow pairs)
        const unsigned int w0 = pack2(S[0], S[1]);    // k{0,1}+4hi
        const unsigned int w1 = pack2(S[2], S[3]);    // k{2,3}+4hi
        const unsigned int w2 = pack2(S[4], S[5]);    // k{8,9}+4hi
        const unsigned int w3 = pack2(S[6], S[7]);    // k{10,11}+4hi
        const unsigned int w4 = pack2(S[8], S[9]);    // k{16,17}+4hi
        const unsigned int w5 = pack2(S[10], S[11]);  // k{18,19}+4hi
        const unsigned int w6 = pack2(S[12], S[13]);  // k{24,25}+4hi
        const unsigned int w7 = pack2(S[14], S[15]);  // k{26,27}+4hi
        // partner-half copies
        const unsigned int x0 = __shfl_xor(w0, 32);
        const unsigned int x1 = __shfl_xor(w1, 32);
        const unsigned int x2 = __shfl_xor(w2, 32);
        const unsigned int x3 = __shfl_xor(w3, 32);
        const unsigned int x4 = __shfl_xor(w4, 32);
        const unsigned int x5 = __shfl_xor(w5, 32);
        const unsigned int x6 = __shfl_xor(w6, 32);
        const unsigned int x7 = __shfl_xor(w7, 32);
        // B-operand fragments: lane needs P[q=ql][k = hi*8 + j] (+16 for pb1)
        union { u32x4 u; short8 s8; } pb0, pb1;
        pb0.u = (u32x4){hi ? x2 : w0, hi ? x3 : w1, hi ? w2 : x0, hi ? w3 : x1};
        pb1.u = (u32x4){hi ? x6 : w4, hi ? x7 : w5, hi ? w6 : x4, hi ? w7 : x5};

        // O^T += V^T @ P^T  (col = q, row = d)
        const short8 vf00 = *(const short8*)&Vs[ql][hi * 8];
        const short8 vf01 = *(const short8*)&Vs[ql][16 + hi * 8];
        const short8 vf10 = *(const short8*)&Vs[32 + ql][hi * 8];
        const short8 vf11 = *(const short8*)&Vs[32 + ql][16 + hi * 8];
        o0 = mfma32(vf00, pb0.s8, o0);
        o0 = mfma32(vf01, pb1.s8, o0);
        o1 = mfma32(vf10, pb0.s8, o1);
        o1 = mfma32(vf11, pb1.s8, o1);
    }

    const float linv = 1.0f / l;
    unsigned short* opbase = &OP[((size_t)qg * B_ + b) * E_ + h * D_];
#pragma unroll
    for (int rp = 0; rp < 8; ++rp) {
        const int r0 = rp * 2, r1 = r0 + 1;
        const int d = ((r0 & 3) + 8 * (r0 >> 2)) + 4 * hi;
        *(unsigned int*)(opbase + d) = pack2(o0[r0] * linv, o0[r1] * linv);
        *(unsigned int*)(opbase + 32 + d) = pack2(o1[r0] * linv, o1[r1] * linv);
    }
    if (hi == 0) {
        Mst[(size_t)bh * SQ_ + qg] = m;
        Lst[(size_t)bh * SQ_ + qg] = l;
    }
}

// ---------------------------------------------------------------------------
// attn-mean pass: recompute scores per (b, q-tile, k-tile), sum over heads.
// (Q already carries the 1/8 scale.)
// ---------------------------------------------------------------------------
__global__ __launch_bounds__(256, 2)
void attn_probs_kernel(const unsigned short* __restrict__ Qb, const unsigned short* __restrict__ Kb,
                       const float* __restrict__ Mst, const float* __restrict__ Lst,
                       const unsigned char* __restrict__ condm, float* __restrict__ out1) {
    const int kv0 = blockIdx.x * 32;
    const int b = blockIdx.z;
    const int t = threadIdx.x, w = t >> 6, lane = t & 63;
    const int lr = lane & 15, lg = lane >> 4, lk = lg * 8;
    const int qbase = blockIdx.y * 64 + w * 16;

    __shared__ unsigned short Ks[32][72];

    int qrow[4], ci[4];
#pragma unroll
    for (int r = 0; r < 4; ++r) {
        qrow[r] = qbase + lg * 4 + r;
        ci[r] = condm[b * SQ_ + qrow[r]];
    }

    bool msk[2][4];
#pragma unroll
    for (int ni = 0; ni < 2; ++ni) {
        const int k = kv0 + ni * 16 + lr;
        int cj = 0, jvalid = 0;
        if (k >= 1 && k < SKV_) { cj = condm[b * SQ_ + k - 1]; jvalid = 1; }
#pragma unroll
        for (int r = 0; r < 4; ++r) {
            if (k == 0) msk[ni][r] = false;
            else if (!jvalid) msk[ni][r] = true;
            else msk[ni][r] = ci[r] ? (cj == 0) : (qrow[r] < (k - 1));
        }
    }

    float acc[2][4] = {};
    const int skey = t >> 3, sdc = (t & 7) * 8;
    const f32x4 zz = {0.f, 0.f, 0.f, 0.f};

#pragma unroll 1
    for (int h = 0; h < H_; ++h) {
        const int bh = b * H_ + h;
        __syncthreads();
        *(short8*)&Ks[skey][sdc] = *(const short8*)&Kb[((size_t)bh * SKVP_ + kv0 + skey) * D_ + sdc];
        __syncthreads();
        const size_t qoff = ((size_t)bh * SQ_ + qbase + lr) * D_;
        const short8 qf0 = *(const short8*)&Qb[qoff + lk];
        const short8 qf1 = *(const short8*)&Qb[qoff + 32 + lk];
        f32x4 S[2];
#pragma unroll
        for (int ni = 0; ni < 2; ++ni) {
            short8 kb0 = *(const short8*)&Ks[ni * 16 + lr][lk];
            short8 kb1 = *(const short8*)&Ks[ni * 16 + lr][32 + lk];
            S[ni] = mfma16(qf0, kb0, zz);
            S[ni] = mfma16(qf1, kb1, S[ni]);
        }
        float mr[4], li[4];
#pragma unroll
        for (int r = 0; r < 4; ++r) {
            mr[r] = Mst[(size_t)bh * SQ_ + qrow[r]];
            li[r] = 1.0f / Lst[(size_t)bh * SQ_ + qrow[r]];
        }
#pragma unroll
        for (int ni = 0; ni < 2; ++ni)
#pragma unroll
            for (int r = 0; r < 4; ++r)
                if (!msk[ni][r]) acc[ni][r] += __expf(S[ni][r] - mr[r]) * li[r];
    }

#pragma unroll
    for (int ni = 0; ni < 2; ++ni) {
        const int k = kv0 + ni * 16 + lr;
        if (k < SKV_) {
#pragma unroll
            for (int r = 0; r < 4; ++r)
                out1[((size_t)b * SQ_ + qrow[r]) * SKV_ + k] = acc[ni][r] * (1.0f / 16.0f);
        }
    }
}

// ---------------------------------------------------------------------------
extern "C" void kernel_launch(void* const* d_in, const int* in_sizes, int n_in,
                              void* d_out, int out_size, void* d_ws, size_t ws_size,
                              hipStream_t stream) {
    const float* q   = (const float*)d_in[0];
    const float* kv  = (const float*)d_in[1];
    const void*  msk = d_in[2];
    const float* Wq  = (const float*)d_in[3];
    const float* bq  = (const float*)d_in[4];
    const float* Wk  = (const float*)d_in[5];
    const float* bk  = (const float*)d_in[6];
    const float* Wv  = (const float*)d_in[7];
    const float* bv  = (const float*)d_in[8];
    const float* Wo  = (const float*)d_in[9];
    const float* bo  = (const float*)d_in[10];

    char* ws = (char*)d_ws;
    unsigned short* Qb  = (unsigned short*)(ws);              // 16,777,216 B
    unsigned short* Kb  = (unsigned short*)(ws + 16777216);   // 17,039,360 B
    unsigned short* Vt  = (unsigned short*)(ws + 33816576);   // 17,039,360 B
    unsigned short* OP  = (unsigned short*)(ws + 50855936);   // 16,777,216 B
    float*          Mst = (float*)(ws + 67633152);            //    524,288 B
    float*          Lst = (float*)(ws + 68157440);            //    524,288 B
    unsigned char* condm = (unsigned char*)(ws + 68681728);   //      8,192 B

    float* out0 = (float*)d_out;
    float* out1 = out0 + (size_t)SQ_ * B_ * E_;

    decode_mask_kernel<<<1, 256, 0, stream>>>(msk, condm);
    gemm_kernel<0><<<dim3(128, 16), 256, 0, stream>>>((const void*)q, Wq, bq, (void*)Qb, SQ_ * B_);
    gemm_kernel<1><<<dim3(129, 16), 256, 0, stream>>>((const void*)kv, Wk, bk, (void*)Kb, SKV_ * B_);
    gemm_kernel<2><<<dim3(129, 16), 256, 0, stream>>>((const void*)kv, Wv, bv, (void*)Vt, SKV_ * B_);
    zero_pad_kernel<<<992, 256, 0, stream>>>(Kb, Vt);
    attn_fwd_kernel<<<dim3(16, 16, 4), 256, 0, stream>>>(Qb, Kb, Vt, condm, OP, Mst, Lst);
    attn_probs_kernel<<<dim3(65, 32, 4), 256, 0, stream>>>(Qb, Kb, Mst, Lst, condm, out1);
    gemm_kernel<3><<<dim3(128, 16), 256, 0, stream>>>((const void*)OP, Wo, bo, (void*)out0, SQ_ * B_);
}